// Round 11
// baseline (616.451 us; speedup 1.0000x reference)
//
#include <hip/hip_runtime.h>

// ---------------------------------------------------------------------------
// BlockCrossAttention on MI355X (gfx950).  Round 11 (= r10 + fusion/XCD):
//  - gemm_qkv KV: XCD-aware swizzle (all n-tiles of an m-tile on one XCD ->
//    A staged once per XCD instead of 8x).
//  - flash_attn: combine fused in via threadfence + atomic last-finisher
//    (4 split-WGs per tile are bx%8-equal -> same XCD, L2-local partials).
//  - gemm_o: split-K partial sum + x16 broadcast fused in the same way.
//  - 6 kernels -> 4.  prep zeroes the atomic counters each call.
// ---------------------------------------------------------------------------

typedef unsigned short u16;
typedef unsigned int u32;
typedef __attribute__((ext_vector_type(8))) __bf16 bf16x8;
typedef __attribute__((ext_vector_type(4))) float f32x4;
typedef __attribute__((ext_vector_type(4))) _Float16 f16x4;

static __device__ __forceinline__ u16 f2bf(float f) {        // RNE
    unsigned int u = __float_as_uint(f);
    u = (u + 0x7fffu + ((u >> 16) & 1u)) >> 16;
    return (u16)u;
}
static __device__ __forceinline__ void gload16(const u16* g, u16* l) {
    __builtin_amdgcn_global_load_lds(
        (const __attribute__((address_space(1))) void*)g,
        (__attribute__((address_space(3))) void*)l, 16, 0, 0);
}

// ---------------- all prep in one launch -----------------------------------
// [0,1024) pool, [1024,3072) enc cast (x4 ILP), [3072,5632) transposes,
// 5632: mask -> f16 + zero atomic counters.
__global__ __launch_bounds__(256) void prep_all(const float* __restrict__ enc,
                                                const float* __restrict__ hid,
                                                const int* __restrict__ mask,
                                                const float* __restrict__ Wq,
                                                const float* __restrict__ Wk,
                                                const float* __restrict__ Wv,
                                                const float* __restrict__ Wo,
                                                u16* __restrict__ encb,
                                                u16* __restrict__ poolb,
                                                u16* __restrict__ mh,
                                                u16* __restrict__ Wq_t,
                                                u16* __restrict__ Wkv_t,
                                                u16* __restrict__ Wo_t,
                                                u32* __restrict__ cntF,
                                                u32* __restrict__ cntO) {
    int bid = blockIdx.x;
    if (bid < 1024) {                                  // mean-pool 16 tokens
        const int tid = bid * 256 + threadIdx.x;
        const int c4 = tid & 255;
        const int row = tid >> 8;                      // b*512 + n
        const float4* src = (const float4*)(hid + (size_t)row * 16 * 1024) + c4;
        float4 a = src[0];
#pragma unroll
        for (int t = 1; t < 16; ++t) {
            float4 b = src[(size_t)t * 256];
            a.x += b.x; a.y += b.y; a.z += b.z; a.w += b.w;
        }
        ushort4 o;
        o.x = f2bf(a.x * 0.0625f); o.y = f2bf(a.y * 0.0625f);
        o.z = f2bf(a.z * 0.0625f); o.w = f2bf(a.w * 0.0625f);
        *(ushort4*)(poolb + (size_t)row * 1024 + c4 * 4) = o;
    } else if (bid < 3072) {                           // enc fp32->bf16, x4 ILP
        const int base = (bid - 1024) * 1024 + threadIdx.x;
        float4 v[4];
#pragma unroll
        for (int j = 0; j < 4; ++j) v[j] = ((const float4*)enc)[base + j * 256];
#pragma unroll
        for (int j = 0; j < 4; ++j) {
            ushort4 o;
            o.x = f2bf(v[j].x); o.y = f2bf(v[j].y);
            o.z = f2bf(v[j].z); o.w = f2bf(v[j].w);
            ((ushort4*)encb)[base + j * 256] = o;
        }
    } else if (bid < 5632) {                           // weight transpose+cast
        bid -= 3072;
        const float* in; u16* out; int N, nbx, rowoff;
        if (bid < 1024)      { in = Wq; out = Wq_t;  N = 1024; nbx = 32; rowoff = 0; }
        else if (bid < 2048) { in = Wo; out = Wo_t;  N = 1024; nbx = 32; rowoff = 0; bid -= 1024; }
        else if (bid < 2304) { in = Wk; out = Wkv_t; N = 256;  nbx = 8;  rowoff = 0; bid -= 2048; }
        else                 { in = Wv; out = Wkv_t; N = 256;  nbx = 8;  rowoff = 256; bid -= 2304; }
        const int n0 = (bid % nbx) * 32, k0 = (bid / nbx) * 32;
        __shared__ float t[32][33];
        const int tx = threadIdx.x & 31, ty = threadIdx.x >> 5;
#pragma unroll
        for (int i = 0; i < 4; ++i)
            t[ty + 8 * i][tx] = in[(size_t)(k0 + ty + 8 * i) * N + n0 + tx];
        __syncthreads();
#pragma unroll
        for (int i = 0; i < 4; ++i)
            out[(size_t)(rowoff + n0 + ty + 8 * i) * 1024 + k0 + tx] = f2bf(t[tx][ty + 8 * i]);
    } else {                                           // mask -> f16 + counters
#pragma unroll
        for (int k = 0; k < 32; ++k) {
            const int i = threadIdx.x + 256 * k;
            mh[i] = mask[i] ? (u16)0x3C00 : (u16)0;    // f16 1.0 / 0.0
        }
        cntF[threadIdx.x] = 0;
        cntO[threadIdx.x] = 0;
    }
}

// ---------------- 64x64 GEMM core (shared mem passed in) -------------------
template <int MODE>
static __device__ __forceinline__ void gemm_core(const u16* __restrict__ A,
                                                 const u16* __restrict__ Bt,
                                                 u16* __restrict__ outQ,
                                                 float* __restrict__ out_f,
                                                 int m0, int n0, int kt0, int nkt,
                                                 u16* sAB) {
    u16* sA = sAB;
    u16* sB = sAB + 64 * 64;
    const int t = threadIdx.x;
    const int w = t >> 6, lane = t & 63, quad = lane >> 4, r16 = lane & 15;
    const int row8 = lane >> 3, seg = lane & 7;

    f32x4 acc[4];
#pragma unroll
    for (int i = 0; i < 4; ++i) acc[i] = (f32x4){0.f, 0.f, 0.f, 0.f};

    for (int kt = kt0; kt < kt0 + nkt; ++kt) {
        const int k0 = kt * 64;
        __syncthreads();
#pragma unroll
        for (int j = 0; j < 2; ++j) {
            const int ra = w * 16 + j * 8;
            gload16(A + (size_t)(m0 + ra + row8) * 1024 + k0 + seg * 8, sA + ra * 64);
            gload16(Bt + (size_t)(n0 + ra + row8) * 1024 + k0 + seg * 8, sB + ra * 64);
        }
        __syncthreads();
#pragma unroll
        for (int kk = 0; kk < 2; ++kk) {
            const bf16x8 af = *(const bf16x8*)(sA + (16 * w + r16) * 64 + kk * 32 + quad * 8);
#pragma unroll
            for (int nt = 0; nt < 4; ++nt) {
                const bf16x8 bfv = *(const bf16x8*)(sB + (nt * 16 + r16) * 64 + kk * 32 + quad * 8);
                acc[nt] = __builtin_amdgcn_mfma_f32_16x16x32_bf16(af, bfv, acc[nt], 0, 0, 0);
            }
        }
    }

    if (MODE == 0) {
#pragma unroll
        for (int nt = 0; nt < 4; ++nt)
#pragma unroll
            for (int r = 0; r < 4; ++r) {
                const int m = m0 + 16 * w + quad * 4 + r;
                const int c = n0 + nt * 16 + r16;
                const int b = m >> 9, nq = m & 511, g = c >> 8, qh = (c >> 6) & 3, d = c & 63;
                outQ[((((size_t)(b * 4 + g) * 4 + qh) * 512 + nq) << 6) + d] =
                    f2bf(acc[nt][r] * 0.180336880f);   // 0.125*log2(e), exp2 domain
            }
    } else {                                           // MODE 3: plain fp32
#pragma unroll
        for (int nt = 0; nt < 4; ++nt)
#pragma unroll
            for (int r = 0; r < 4; ++r) {
                const int m = m0 + 16 * w + quad * 4 + r;
                const int c = n0 + nt * 16 + r16;
                out_f[(size_t)m * 1024 + c] = acc[nt][r];
            }
    }
}

// ---------------- Q + KV projection in one launch --------------------------
// bx < 512: KV GEMM 128x64 tile, XCD swizzle: mlo=bx&7 (=XCD), mhi=(bx>>3)&7,
//           n=bx>>6 -> all 8 n-tiles of an m-tile co-resident on one XCD.
// bx >= 512: Q GEMM, 64x64 tile.
__global__ __launch_bounds__(256) void gemm_qkv(const u16* __restrict__ poolb,
                                                const u16* __restrict__ encb,
                                                const u16* __restrict__ Wq_t,
                                                const u16* __restrict__ Wkv_t,
                                                const int* __restrict__ maskp,
                                                u16* __restrict__ Qa,
                                                u16* __restrict__ Ka,
                                                u16* __restrict__ Va) {
    __shared__ __align__(16) u16 smem[12288];          // 24 KB
    const int bx = blockIdx.x;
    if (bx >= 512) {
        const int b = bx - 512;
        gemm_core<0>(poolb, Wq_t, Qa, nullptr, (b >> 4) * 64, (b & 15) * 64, 0, 16, smem);
        return;
    }
    const int mt = (bx & 7) + 8 * ((bx >> 3) & 7);     // [0,64)
    const int m0 = mt * 128, n0 = (bx >> 6) * 64;
    u16* sA = smem;                                    // 128 x 64
    u16* sB = smem + 128 * 64;                         // 64 x 64
    const int t = threadIdx.x;
    const int w = t >> 6, lane = t & 63, quad = lane >> 4, r16 = lane & 15;
    const int row8 = lane >> 3, seg = lane & 7;

    f32x4 acc[2][4];
#pragma unroll
    for (int i = 0; i < 2; ++i)
#pragma unroll
        for (int nt = 0; nt < 4; ++nt) acc[i][nt] = (f32x4){0.f, 0.f, 0.f, 0.f};

    for (int kt = 0; kt < 16; ++kt) {
        const int k0 = kt * 64;
        __syncthreads();
#pragma unroll
        for (int p = 0; p < 4; ++p) {
            const int ra = p * 32 + w * 8;
            gload16(encb + (size_t)(m0 + ra + row8) * 1024 + k0 + seg * 8, sA + ra * 64);
        }
#pragma unroll
        for (int p = 0; p < 2; ++p) {
            const int ra = p * 32 + w * 8;
            gload16(Wkv_t + (size_t)(n0 + ra + row8) * 1024 + k0 + seg * 8, sB + ra * 64);
        }
        __syncthreads();
#pragma unroll
        for (int kk = 0; kk < 2; ++kk)
#pragma unroll
            for (int i = 0; i < 2; ++i) {
                const bf16x8 af = *(const bf16x8*)(sA + (w * 32 + i * 16 + r16) * 64 + kk * 32 + quad * 8);
#pragma unroll
                for (int nt = 0; nt < 4; ++nt) {
                    const bf16x8 bfv = *(const bf16x8*)(sB + (nt * 16 + r16) * 64 + kk * 32 + quad * 8);
                    acc[i][nt] = __builtin_amdgcn_mfma_f32_16x16x32_bf16(af, bfv, acc[i][nt], 0, 0, 0);
                }
            }
    }

    const bool isV = (n0 >= 256);
    const int g = (isV ? (n0 - 256) : n0) >> 6;
    const int b = m0 >> 12, l0 = m0 & 4095;
    __syncthreads();
    if (isV) {
        u16* sT = smem;                                // 64 d x stride 136 (l)
#pragma unroll
        for (int i = 0; i < 2; ++i) {
            float mfl[4];
#pragma unroll
            for (int r = 0; r < 4; ++r)
                mfl[r] = maskp[b * 4096 + l0 + w * 32 + i * 16 + quad * 4 + r] ? 1.f : 0.f;
#pragma unroll
            for (int nt = 0; nt < 4; ++nt)
#pragma unroll
                for (int r = 0; r < 4; ++r) {
                    const int ml = w * 32 + i * 16 + quad * 4 + r, cl = nt * 16 + r16;
                    union { _Float16 h; u16 u; } cv;
                    cv.h = (_Float16)(acc[i][nt][r] * mfl[r]);
                    sT[cl * 136 + ml] = cv.u;
                }
        }
        __syncthreads();
#pragma unroll
        for (int p = 0; p < 4; ++p) {
            const int idx = t + 256 * p, rr = idx >> 4, ch = idx & 15;
            *(int4*)(Va + ((size_t)(b * 4 + g) * 64 + rr) * 4096 + l0 + ch * 8) =
                *(const int4*)(sT + rr * 136 + ch * 8);
        }
    } else {
        u16* sT = smem;                                // 128 l x stride 72 (d)
#pragma unroll
        for (int i = 0; i < 2; ++i)
#pragma unroll
            for (int nt = 0; nt < 4; ++nt)
#pragma unroll
                for (int r = 0; r < 4; ++r) {
                    const int ml = w * 32 + i * 16 + quad * 4 + r, cl = nt * 16 + r16;
                    sT[ml * 72 + cl] = f2bf(acc[i][nt][r]);
                }
        __syncthreads();
#pragma unroll
        for (int p = 0; p < 4; ++p) {
            const int idx = t + 256 * p, rr = idx >> 3, ch = idx & 7;
            *(int4*)(Ka + (((size_t)(b * 4 + g) * 4096 + l0 + rr) << 6) + ch * 8) =
                *(const int4*)(sT + rr * 72 + ch * 8);
        }
    }
}

// ---------------- flash attention + fused combine --------------------------
// grid 1024: bx = s16*32 + (gb*4+split)  -> the 4 splits of a tile and the 32
// s16-WGs of a (gb,split) K-chunk share bx%8 (same XCD). Last split-WG per
// (gb,s16) combines all 4 qh and writes normalized attn.
__global__ __launch_bounds__(256, 4) void flash_attn(const u16* __restrict__ Qa,
                                                     const u16* __restrict__ Ka,
                                                     const u16* __restrict__ Vt,
                                                     const u16* __restrict__ mh,
                                                     float* __restrict__ Opart,
                                                     float* __restrict__ mlpart,
                                                     u16* __restrict__ attnout,
                                                     u32* __restrict__ cntF) {
    const int bx = blockIdx.x;
    const int s16 = bx >> 5, rr = bx & 31;
    const int split = rr & 3, gb = rr >> 2;
    const int g = gb & 3, b = gb >> 2;
    __shared__ __align__(16) u16 sK[64 * 72];        // [l][d] bf16
    __shared__ __align__(16) u16 sV[64 * 68];        // [d][l] f16 (V^T)
    __shared__ int sLast;
    const int t = threadIdx.x;
    const int qh = t >> 6, lane = t & 63, quad = lane >> 4, r16 = lane & 15;

    bf16x8 aq[2];
    {
        const size_t qbase = ((((size_t)(b * 4 + g) * 4 + qh) * 512) + s16 * 16 + r16) * 64;
#pragma unroll
        for (int kk = 0; kk < 2; ++kk)
            aq[kk] = *(const bf16x8*)(Qa + qbase + kk * 32 + quad * 8);
    }
    const u16* Kg = Ka + (size_t)(b * 4 + g) * 4096 * 64 + (size_t)split * 1024 * 64; // [l][d]
    const u16* Vg = Vt + (size_t)(b * 4 + g) * 64 * 4096 + split * 1024;              // [d][l]
    const u16* mb = mh + b * 4096 + split * 1024 + quad * 4;

    f32x4 o[4], lacc;
#pragma unroll
    for (int i = 0; i < 4; ++i) o[i] = (f32x4){0.f, 0.f, 0.f, 0.f};
    lacc = (f32x4){0.f, 0.f, 0.f, 0.f};

    for (int tile = 0; tile < 16; ++tile) {
        const int l0 = tile * 64;
        __syncthreads();
#pragma unroll
        for (int p = 0; p < 2; ++p) {
            const int idx = t + 256 * p, row = idx >> 3, seg = idx & 7;
            *(int4*)(sK + row * 72 + seg * 8) =
                *(const int4*)(Kg + (size_t)(l0 + row) * 64 + seg * 8);
            *(int4*)(sV + row * 68 + seg * 8) =
                *(const int4*)(Vg + (size_t)row * 4096 + l0 + seg * 8);
        }
        __syncthreads();

        f32x4 st[4];
#pragma unroll
        for (int nt = 0; nt < 4; ++nt) st[nt] = (f32x4){0.f, 0.f, 0.f, 0.f};
#pragma unroll
        for (int kk = 0; kk < 2; ++kk)
#pragma unroll
            for (int nt = 0; nt < 4; ++nt) {
                const bf16x8 ka = *(const bf16x8*)(sK + (nt * 16 + r16) * 72 + kk * 32 + quad * 8);
                st[nt] = __builtin_amdgcn_mfma_f32_16x16x32_bf16(ka, aq[kk], st[nt], 0, 0, 0);
            }

#pragma unroll
        for (int nt = 0; nt < 4; ++nt) {
            f16x4 pa;
#pragma unroll
            for (int j = 0; j < 4; ++j)
                pa[j] = (_Float16)__builtin_amdgcn_exp2f(st[nt][j]);
            const f16x4 bvm = *(const f16x4*)(mb + l0 + nt * 16);
            lacc = __builtin_amdgcn_mfma_f32_16x16x16f16(pa, bvm, lacc, 0, 0, 0);
#pragma unroll
            for (int dt = 0; dt < 4; ++dt) {
                const f16x4 bv = *(const f16x4*)(sV + (dt * 16 + r16) * 68 + nt * 16 + quad * 4);
                o[dt] = __builtin_amdgcn_mfma_f32_16x16x16f16(pa, bv, o[dt], 0, 0, 0);
            }
        }
    }

    // partials: part id = ((gb*4+split) + 32*s16)*4 + qh
    const size_t pbase = ((size_t)bx * 4 + qh) * 1024;
#pragma unroll
    for (int dt = 0; dt < 4; ++dt)
#pragma unroll
        for (int r = 0; r < 4; ++r)
            Opart[pbase + (size_t)(quad * 4 + r) * 64 + dt * 16 + r16] = o[dt][r];
    if (r16 == 0) {
#pragma unroll
        for (int r = 0; r < 4; ++r)
            mlpart[((size_t)bx * 4 + qh) * 16 + quad * 4 + r] = lacc[r];
    }

    // last-finisher combine for (gb, s16)
    __threadfence();
    __syncthreads();                                   // all stores drained
    if (t == 0) sLast = (atomicAdd(&cntF[gb * 32 + s16], 1) == 3);
    __syncthreads();
    if (!sLast) return;
    __threadfence();                                   // acquire other WGs' data

    const int q = t >> 4, dg = t & 15;
#pragma unroll
    for (int qqh = 0; qqh < 4; ++qqh) {
        float4 a = make_float4(0.f, 0.f, 0.f, 0.f);
        float L = 0.f;
#pragma unroll
        for (int s = 0; s < 4; ++s) {
            const size_t part = ((size_t)((gb * 4 + s) + 32 * s16) * 4 + qqh);
            const float4 v = *(const float4*)(Opart + part * 1024 + q * 64 + dg * 4);
            a.x += v.x; a.y += v.y; a.z += v.z; a.w += v.w;
            L += mlpart[part * 16 + q];
        }
        const float invL = 1.f / L;
        ushort4 ov;
        ov.x = f2bf(a.x * invL); ov.y = f2bf(a.y * invL);
        ov.z = f2bf(a.z * invL); ov.w = f2bf(a.w * invL);
        *(ushort4*)(attnout + ((size_t)b * 512 + s16 * 16 + q) * 1024 +
                    (g * 4 + qqh) * 64 + dg * 4) = ov;
    }
}

// ---------------- O projection (split-K-4) + fused sum/broadcast -----------
// grid 1024: bx = s*256 + mn. Last split-WG per mn sums the 4 partials and
// broadcasts x16 to token level.
__global__ __launch_bounds__(256) void gemm_o(const u16* __restrict__ attn,
                                              const u16* __restrict__ Wo_t,
                                              float* __restrict__ blkpart,
                                              float* __restrict__ out,
                                              u32* __restrict__ cntO) {
    __shared__ __align__(16) u16 smem[8192];           // 16 KB
    __shared__ int sLast;
    const int bx = blockIdx.x;
    const int s = bx >> 8, mn = bx & 255;
    const int m0 = ((bx >> 4) & 15) * 64, n0 = (bx & 15) * 64;
    gemm_core<3>(attn, Wo_t, nullptr, blkpart + ((size_t)s << 20), m0, n0, s * 4, 4, smem);

    const int t = threadIdx.x;
    __threadfence();
    __syncthreads();
    if (t == 0) sLast = (atomicAdd(&cntO[mn], 1) == 3);
    __syncthreads();
    if (!sLast) return;
    __threadfence();

#pragma unroll
    for (int j = 0; j < 4; ++j) {
        const int idx = t + 256 * j, rowl = idx >> 4, c4l = idx & 15;
        float4 a = make_float4(0.f, 0.f, 0.f, 0.f);
#pragma unroll
        for (int ss = 0; ss < 4; ++ss) {
            const float4 v = ((const float4*)blkpart)[(ss << 18) + ((m0 + rowl) << 8) + (n0 >> 2) + c4l];
            a.x += v.x; a.y += v.y; a.z += v.z; a.w += v.w;
        }
        const int m = m0 + rowl, b = m >> 9, n = m & 511;
        float4* dst = (float4*)out + (((size_t)b * 8192 + n * 16) << 8) + (n0 >> 2) + c4l;
#pragma unroll
        for (int rep = 0; rep < 16; ++rep)
            dst[(size_t)rep << 8] = a;
    }
}

// ---------------------------------------------------------------------------
extern "C" void kernel_launch(void* const* d_in, const int* in_sizes, int n_in,
                              void* d_out, int out_size, void* d_ws, size_t ws_size,
                              hipStream_t stream) {
    const float* hid  = (const float*)d_in[0];
    const float* enc  = (const float*)d_in[1];
    const int*   mask = (const int*)d_in[2];
    const float* Wq   = (const float*)d_in[3];
    const float* Wk   = (const float*)d_in[4];
    const float* Wv   = (const float*)d_in[5];
    const float* Wo   = (const float*)d_in[6];
    float* out = (float*)d_out;

    char* ws = (char*)d_ws;
    size_t off = 0;
    auto alloc = [&](size_t bytes) -> char* {
        char* p = ws + off;
        off += (bytes + 255) & ~(size_t)255;
        return p;
    };
    u16* Wq_t  = (u16*)alloc((size_t)1024 * 1024 * 2);
    u16* Wkv_t = (u16*)alloc((size_t)512 * 1024 * 2);
    u16* Wo_t  = (u16*)alloc((size_t)1024 * 1024 * 2);
    u16* encb  = (u16*)alloc((size_t)8192 * 1024 * 2);     // 16 MB
    u16* poolb = (u16*)alloc((size_t)1024 * 1024 * 2);     // 2 MB
    u16* Qa    = (u16*)alloc((size_t)1024 * 1024 * 2);
    u16* Ka    = (u16*)alloc((size_t)8 * 4096 * 64 * 2);   // bf16 [l][d]
    u16* Va    = (u16*)alloc((size_t)8 * 4096 * 64 * 2);   // f16  [d][l], masked
    u16* attn  = (u16*)alloc((size_t)1024 * 1024 * 2);
    u16* mh    = (u16*)alloc((size_t)8192 * 2);            // f16 0/1 mask
    u32* cntF  = (u32*)alloc(256 * 4);
    u32* cntO  = (u32*)alloc(256 * 4);
    // stream-ordered aliases of encb (16 MB):
    //   flash writes/reads Opart -> gemm_o writes/reads blkpart
    float* Opart   = (float*)encb;   // 4096 x 16x64 fp32 = 16 MB
    float* blkpart = (float*)encb;   // 4 x 1024 x 1024 fp32 = 16 MB
    float* mlpart  = (float*)poolb;  // 4096 x 16 fp32 = 256 KB (dead after Q-GEMM)

    prep_all<<<5633, 256, 0, stream>>>(enc, hid, mask, Wq, Wk, Wv, Wo,
                                       encb, poolb, mh, Wq_t, Wkv_t, Wo_t, cntF, cntO);
    gemm_qkv<<<768, 256, 0, stream>>>(poolb, encb, Wq_t, Wkv_t, mask, Qa, Ka, Va);
    flash_attn<<<1024, 256, 0, stream>>>(Qa, Ka, Va, mh, Opart, mlpart, attn, cntF);
    gemm_o<<<1024, 256, 0, stream>>>(attn, Wo_t, blkpart, out, cntO);
}

// Round 13
// 243.664 us; speedup vs baseline: 2.5299x; 2.5299x over previous
//
#include <hip/hip_runtime.h>

// ---------------------------------------------------------------------------
// BlockCrossAttention on MI355X (gfx950).  Round 13 = r10 structure
// (best: 243.6 us) + nontemporal output stores (fixed: native ext-vector
// type for __builtin_nontemporal_store, not HIP float4).
// ---------------------------------------------------------------------------

typedef unsigned short u16;
typedef __attribute__((ext_vector_type(8))) __bf16 bf16x8;
typedef __attribute__((ext_vector_type(4))) float f32x4;
typedef __attribute__((ext_vector_type(4))) _Float16 f16x4;

static __device__ __forceinline__ u16 f2bf(float f) {        // RNE
    unsigned int u = __float_as_uint(f);
    u = (u + 0x7fffu + ((u >> 16) & 1u)) >> 16;
    return (u16)u;
}
static __device__ __forceinline__ void gload16(const u16* g, u16* l) {
    __builtin_amdgcn_global_load_lds(
        (const __attribute__((address_space(1))) void*)g,
        (__attribute__((address_space(3))) void*)l, 16, 0, 0);
}

// ---------------- all prep in one launch (heavy-first) ---------------------
__global__ __launch_bounds__(256) void prep_all(const float* __restrict__ enc,
                                                const float* __restrict__ hid,
                                                const int* __restrict__ mask,
                                                const float* __restrict__ Wq,
                                                const float* __restrict__ Wk,
                                                const float* __restrict__ Wv,
                                                const float* __restrict__ Wo,
                                                u16* __restrict__ encb,
                                                u16* __restrict__ poolb,
                                                u16* __restrict__ mh,
                                                u16* __restrict__ Wq_t,
                                                u16* __restrict__ Wkv_t,
                                                u16* __restrict__ Wo_t) {
    int bid = blockIdx.x;
    if (bid < 1024) {                                  // mean-pool 16 tokens
        const int tid = bid * 256 + threadIdx.x;
        const int c4 = tid & 255;
        const int row = tid >> 8;                      // b*512 + n
        const float4* src = (const float4*)(hid + (size_t)row * 16 * 1024) + c4;
        float4 a = src[0];
#pragma unroll
        for (int t = 1; t < 16; ++t) {
            float4 b = src[(size_t)t * 256];
            a.x += b.x; a.y += b.y; a.z += b.z; a.w += b.w;
        }
        ushort4 o;
        o.x = f2bf(a.x * 0.0625f); o.y = f2bf(a.y * 0.0625f);
        o.z = f2bf(a.z * 0.0625f); o.w = f2bf(a.w * 0.0625f);
        *(ushort4*)(poolb + (size_t)row * 1024 + c4 * 4) = o;
    } else if (bid < 3072) {                           // enc fp32->bf16, x4 ILP
        const int base = (bid - 1024) * 1024 + threadIdx.x;
        float4 v[4];
#pragma unroll
        for (int j = 0; j < 4; ++j) v[j] = ((const float4*)enc)[base + j * 256];
#pragma unroll
        for (int j = 0; j < 4; ++j) {
            ushort4 o;
            o.x = f2bf(v[j].x); o.y = f2bf(v[j].y);
            o.z = f2bf(v[j].z); o.w = f2bf(v[j].w);
            ((ushort4*)encb)[base + j * 256] = o;
        }
    } else if (bid < 5632) {                           // weight transpose+cast
        bid -= 3072;
        const float* in; u16* out; int N, nbx, rowoff;
        if (bid < 1024)      { in = Wq; out = Wq_t;  N = 1024; nbx = 32; rowoff = 0; }
        else if (bid < 2048) { in = Wo; out = Wo_t;  N = 1024; nbx = 32; rowoff = 0; bid -= 1024; }
        else if (bid < 2304) { in = Wk; out = Wkv_t; N = 256;  nbx = 8;  rowoff = 0; bid -= 2048; }
        else                 { in = Wv; out = Wkv_t; N = 256;  nbx = 8;  rowoff = 256; bid -= 2304; }
        const int n0 = (bid % nbx) * 32, k0 = (bid / nbx) * 32;
        __shared__ float t[32][33];
        const int tx = threadIdx.x & 31, ty = threadIdx.x >> 5;
#pragma unroll
        for (int i = 0; i < 4; ++i)
            t[ty + 8 * i][tx] = in[(size_t)(k0 + ty + 8 * i) * N + n0 + tx];
        __syncthreads();
#pragma unroll
        for (int i = 0; i < 4; ++i)
            out[(size_t)(rowoff + n0 + ty + 8 * i) * 1024 + k0 + tx] = f2bf(t[tx][ty + 8 * i]);
    } else {                                           // mask -> f16 0/1
#pragma unroll
        for (int k = 0; k < 32; ++k) {
            const int i = threadIdx.x + 256 * k;
            mh[i] = mask[i] ? (u16)0x3C00 : (u16)0;    // f16 1.0 / 0.0
        }
    }
}

// ---------------- 64x64 GEMM core (shared mem passed in) -------------------
// MODE 0: Q -> Qa scatter * 0.125*log2e.  MODE 3: fp32 out[m*1024+c].
template <int MODE>
static __device__ __forceinline__ void gemm_core(const u16* __restrict__ A,
                                                 const u16* __restrict__ Bt,
                                                 u16* __restrict__ outQ,
                                                 float* __restrict__ out_f,
                                                 int m0, int n0, int kt0, int nkt,
                                                 u16* sAB) {
    u16* sA = sAB;
    u16* sB = sAB + 64 * 64;
    const int t = threadIdx.x;
    const int w = t >> 6, lane = t & 63, quad = lane >> 4, r16 = lane & 15;
    const int row8 = lane >> 3, seg = lane & 7;

    f32x4 acc[4];
#pragma unroll
    for (int i = 0; i < 4; ++i) acc[i] = (f32x4){0.f, 0.f, 0.f, 0.f};

    for (int kt = kt0; kt < kt0 + nkt; ++kt) {
        const int k0 = kt * 64;
        __syncthreads();
#pragma unroll
        for (int j = 0; j < 2; ++j) {
            const int ra = w * 16 + j * 8;
            gload16(A + (size_t)(m0 + ra + row8) * 1024 + k0 + seg * 8, sA + ra * 64);
            gload16(Bt + (size_t)(n0 + ra + row8) * 1024 + k0 + seg * 8, sB + ra * 64);
        }
        __syncthreads();
#pragma unroll
        for (int kk = 0; kk < 2; ++kk) {
            const bf16x8 af = *(const bf16x8*)(sA + (16 * w + r16) * 64 + kk * 32 + quad * 8);
#pragma unroll
            for (int nt = 0; nt < 4; ++nt) {
                const bf16x8 bfv = *(const bf16x8*)(sB + (nt * 16 + r16) * 64 + kk * 32 + quad * 8);
                acc[nt] = __builtin_amdgcn_mfma_f32_16x16x32_bf16(af, bfv, acc[nt], 0, 0, 0);
            }
        }
    }

    if (MODE == 0) {
#pragma unroll
        for (int nt = 0; nt < 4; ++nt)
#pragma unroll
            for (int r = 0; r < 4; ++r) {
                const int m = m0 + 16 * w + quad * 4 + r;
                const int c = n0 + nt * 16 + r16;
                const int b = m >> 9, nq = m & 511, g = c >> 8, qh = (c >> 6) & 3, d = c & 63;
                outQ[((((size_t)(b * 4 + g) * 4 + qh) * 512 + nq) << 6) + d] =
                    f2bf(acc[nt][r] * 0.180336880f);   // 0.125*log2(e), exp2 domain
            }
    } else {                                           // MODE 3: plain fp32
#pragma unroll
        for (int nt = 0; nt < 4; ++nt)
#pragma unroll
            for (int r = 0; r < 4; ++r) {
                const int m = m0 + 16 * w + quad * 4 + r;
                const int c = n0 + nt * 16 + r16;
                out_f[(size_t)m * 1024 + c] = acc[nt][r];
            }
    }
}

// ---------------- Q + KV projection in one launch --------------------------
// bx < 512: KV GEMM, 128x64 tile (m0 = (bx>>3)*128, n-inner swizzle).
// bx >= 512: Q GEMM, 64x64 tile.
__global__ __launch_bounds__(256) void gemm_qkv(const u16* __restrict__ poolb,
                                                const u16* __restrict__ encb,
                                                const u16* __restrict__ Wq_t,
                                                const u16* __restrict__ Wkv_t,
                                                const int* __restrict__ maskp,
                                                u16* __restrict__ Qa,
                                                u16* __restrict__ Ka,
                                                u16* __restrict__ Va) {
    __shared__ __align__(16) u16 smem[12288];          // 24 KB
    const int bx = blockIdx.x;
    if (bx >= 512) {
        const int b = bx - 512;
        gemm_core<0>(poolb, Wq_t, Qa, nullptr, (b >> 4) * 64, (b & 15) * 64, 0, 16, smem);
        return;
    }
    const int m0 = (bx >> 3) * 128, n0 = (bx & 7) * 64;
    u16* sA = smem;                                    // 128 x 64
    u16* sB = smem + 128 * 64;                         // 64 x 64
    const int t = threadIdx.x;
    const int w = t >> 6, lane = t & 63, quad = lane >> 4, r16 = lane & 15;
    const int row8 = lane >> 3, seg = lane & 7;

    f32x4 acc[2][4];
#pragma unroll
    for (int i = 0; i < 2; ++i)
#pragma unroll
        for (int nt = 0; nt < 4; ++nt) acc[i][nt] = (f32x4){0.f, 0.f, 0.f, 0.f};

    for (int kt = 0; kt < 16; ++kt) {
        const int k0 = kt * 64;
        __syncthreads();
#pragma unroll
        for (int p = 0; p < 4; ++p) {
            const int ra = p * 32 + w * 8;
            gload16(encb + (size_t)(m0 + ra + row8) * 1024 + k0 + seg * 8, sA + ra * 64);
        }
#pragma unroll
        for (int p = 0; p < 2; ++p) {
            const int ra = p * 32 + w * 8;
            gload16(Wkv_t + (size_t)(n0 + ra + row8) * 1024 + k0 + seg * 8, sB + ra * 64);
        }
        __syncthreads();
#pragma unroll
        for (int kk = 0; kk < 2; ++kk)
#pragma unroll
            for (int i = 0; i < 2; ++i) {
                const bf16x8 af = *(const bf16x8*)(sA + (w * 32 + i * 16 + r16) * 64 + kk * 32 + quad * 8);
#pragma unroll
                for (int nt = 0; nt < 4; ++nt) {
                    const bf16x8 bfv = *(const bf16x8*)(sB + (nt * 16 + r16) * 64 + kk * 32 + quad * 8);
                    acc[i][nt] = __builtin_amdgcn_mfma_f32_16x16x32_bf16(af, bfv, acc[i][nt], 0, 0, 0);
                }
            }
    }

    const bool isV = (n0 >= 256);
    const int g = (isV ? (n0 - 256) : n0) >> 6;
    const int b = m0 >> 12, l0 = m0 & 4095;
    __syncthreads();
    if (isV) {
        u16* sT = smem;                                // 64 d x stride 136 (l)
#pragma unroll
        for (int i = 0; i < 2; ++i) {
            float mfl[4];
#pragma unroll
            for (int r = 0; r < 4; ++r)
                mfl[r] = maskp[b * 4096 + l0 + w * 32 + i * 16 + quad * 4 + r] ? 1.f : 0.f;
#pragma unroll
            for (int nt = 0; nt < 4; ++nt)
#pragma unroll
                for (int r = 0; r < 4; ++r) {
                    const int ml = w * 32 + i * 16 + quad * 4 + r, cl = nt * 16 + r16;
                    union { _Float16 h; u16 u; } cv;
                    cv.h = (_Float16)(acc[i][nt][r] * mfl[r]);
                    sT[cl * 136 + ml] = cv.u;
                }
        }
        __syncthreads();
#pragma unroll
        for (int p = 0; p < 4; ++p) {
            const int idx = t + 256 * p, rr = idx >> 4, ch = idx & 15;
            *(int4*)(Va + ((size_t)(b * 4 + g) * 64 + rr) * 4096 + l0 + ch * 8) =
                *(const int4*)(sT + rr * 136 + ch * 8);
        }
    } else {
        u16* sT = smem;                                // 128 l x stride 72 (d)
#pragma unroll
        for (int i = 0; i < 2; ++i)
#pragma unroll
            for (int nt = 0; nt < 4; ++nt)
#pragma unroll
                for (int r = 0; r < 4; ++r) {
                    const int ml = w * 32 + i * 16 + quad * 4 + r, cl = nt * 16 + r16;
                    sT[ml * 72 + cl] = f2bf(acc[i][nt][r]);
                }
        __syncthreads();
#pragma unroll
        for (int p = 0; p < 4; ++p) {
            const int idx = t + 256 * p, rr = idx >> 3, ch = idx & 7;
            *(int4*)(Ka + (((size_t)(b * 4 + g) * 4096 + l0 + rr) << 6) + ch * 8) =
                *(const int4*)(sT + rr * 72 + ch * 8);
        }
    }
}

// split-K-4: grid 1024, each WG does 4 K-iters, writes fp32 partial tile
__global__ __launch_bounds__(256) void gemm_o(const u16* __restrict__ attn,
                                              const u16* __restrict__ Wo_t,
                                              float* __restrict__ blkpart) {
    __shared__ __align__(16) u16 smem[8192];           // 16 KB
    const int bx = blockIdx.x;
    const int s = bx >> 8, m0 = ((bx >> 4) & 15) * 64, n0 = (bx & 15) * 64;
    gemm_core<3>(attn, Wo_t, nullptr, blkpart + ((size_t)s << 20), m0, n0, s * 4, 4, smem);
}

// ---------------- flash attention: LDS-staged, in-register P ---------------
// grid 1024: bx = ((b*4+g)*4+split)*32 + s16. Waves = 4 qh sharing the staged
// K/V tile. S^T = K·Q^T; p = exp2 -> f16 A-frags; O += P·V; L += P·m.
__global__ __launch_bounds__(256, 4) void flash_attn(const u16* __restrict__ Qa,
                                                     const u16* __restrict__ Ka,
                                                     const u16* __restrict__ Vt,
                                                     const u16* __restrict__ mh,
                                                     float* __restrict__ Opart,
                                                     float* __restrict__ mlpart) {
    const int bx = blockIdx.x;
    const int s16 = bx & 31, rr = bx >> 5;
    const int split = rr & 3, gb = rr >> 2;
    const int g = gb & 3, b = gb >> 2;
    __shared__ __align__(16) u16 sK[64 * 72];        // [l][d] bf16
    __shared__ __align__(16) u16 sV[64 * 68];        // [d][l] f16 (V^T)
    const int t = threadIdx.x;
    const int qh = t >> 6, lane = t & 63, quad = lane >> 4, r16 = lane & 15;

    bf16x8 aq[2];
    {
        const size_t qbase = ((((size_t)(b * 4 + g) * 4 + qh) * 512) + s16 * 16 + r16) * 64;
#pragma unroll
        for (int kk = 0; kk < 2; ++kk)
            aq[kk] = *(const bf16x8*)(Qa + qbase + kk * 32 + quad * 8);
    }
    const u16* Kg = Ka + (size_t)(b * 4 + g) * 4096 * 64 + (size_t)split * 1024 * 64; // [l][d]
    const u16* Vg = Vt + (size_t)(b * 4 + g) * 64 * 4096 + split * 1024;              // [d][l]
    const u16* mb = mh + b * 4096 + split * 1024 + quad * 4;

    f32x4 o[4], lacc;
#pragma unroll
    for (int i = 0; i < 4; ++i) o[i] = (f32x4){0.f, 0.f, 0.f, 0.f};
    lacc = (f32x4){0.f, 0.f, 0.f, 0.f};

    for (int tile = 0; tile < 16; ++tile) {
        const int l0 = tile * 64;
        __syncthreads();
#pragma unroll
        for (int p = 0; p < 2; ++p) {
            const int idx = t + 256 * p, row = idx >> 3, seg = idx & 7;
            *(int4*)(sK + row * 72 + seg * 8) =
                *(const int4*)(Kg + (size_t)(l0 + row) * 64 + seg * 8);
            *(int4*)(sV + row * 68 + seg * 8) =
                *(const int4*)(Vg + (size_t)row * 4096 + l0 + seg * 8);
        }
        __syncthreads();

        // S^T[l][q]: K frags from LDS as A-operand, Q regs as B
        f32x4 st[4];
#pragma unroll
        for (int nt = 0; nt < 4; ++nt) st[nt] = (f32x4){0.f, 0.f, 0.f, 0.f};
#pragma unroll
        for (int kk = 0; kk < 2; ++kk)
#pragma unroll
            for (int nt = 0; nt < 4; ++nt) {
                const bf16x8 ka = *(const bf16x8*)(sK + (nt * 16 + r16) * 72 + kk * 32 + quad * 8);
                st[nt] = __builtin_amdgcn_mfma_f32_16x16x32_bf16(ka, aq[kk], st[nt], 0, 0, 0);
            }

        // p = exp2(s) -> f16 A-frags (P[q][l-chunk]); L and O via MFMA
#pragma unroll
        for (int nt = 0; nt < 4; ++nt) {
            f16x4 pa;
#pragma unroll
            for (int j = 0; j < 4; ++j)
                pa[j] = (_Float16)__builtin_amdgcn_exp2f(st[nt][j]);
            const f16x4 bvm = *(const f16x4*)(mb + l0 + nt * 16);
            lacc = __builtin_amdgcn_mfma_f32_16x16x16f16(pa, bvm, lacc, 0, 0, 0);
#pragma unroll
            for (int dt = 0; dt < 4; ++dt) {
                const f16x4 bv = *(const f16x4*)(sV + (dt * 16 + r16) * 68 + nt * 16 + quad * 4);
                o[dt] = __builtin_amdgcn_mfma_f32_16x16x16f16(pa, bv, o[dt], 0, 0, 0);
            }
        }
    }

    // D layout: row(quad*4+r) = query q, col(r16) = d (o) / replicated (lacc)
    const size_t pbase = ((size_t)bx * 4 + qh) * 1024;
#pragma unroll
    for (int dt = 0; dt < 4; ++dt)
#pragma unroll
        for (int r = 0; r < 4; ++r)
            Opart[pbase + (size_t)(quad * 4 + r) * 64 + dt * 16 + r16] = o[dt][r];
    if (r16 == 0) {
#pragma unroll
        for (int r = 0; r < 4; ++r)
            mlpart[((size_t)bx * 4 + qh) * 16 + quad * 4 + r] = lacc[r];
    }
}

// ---------------- combine 4 split partials -> normalized attn (bf16) -------
__global__ __launch_bounds__(256) void flash_combine(const float* __restrict__ Opart,
                                                     const float* __restrict__ mlpart,
                                                     u16* __restrict__ attnout) {
    const int bx = blockIdx.x;                  // tile (b,g,qh,s16)
    const int s16 = bx & 31, h = bx >> 5;
    const int qh = h & 3, g = (h >> 2) & 3, b = h >> 4;
    const int t = threadIdx.x;
    const int q = t >> 4, dg = t & 15;
    float4 a = make_float4(0.f, 0.f, 0.f, 0.f);
    float L = 0.f;
#pragma unroll
    for (int s = 0; s < 4; ++s) {
        const size_t part = (((size_t)((b * 4 + g) * 4 + s) * 32 + s16) * 4 + qh);
        const float4 v = *(const float4*)(Opart + part * 1024 + q * 64 + dg * 4);
        a.x += v.x; a.y += v.y; a.z += v.z; a.w += v.w;
        L += mlpart[part * 16 + q];
    }
    const float invL = 1.f / L;
    ushort4 ov;
    ov.x = f2bf(a.x * invL); ov.y = f2bf(a.y * invL);
    ov.z = f2bf(a.z * invL); ov.w = f2bf(a.w * invL);
    *(ushort4*)(attnout + ((size_t)b * 512 + s16 * 16 + q) * 1024 +
                (g * 4 + qh) * 64 + dg * 4) = ov;
}

// ---------------- sum split-K partials + broadcast x16 (NT stores) ---------
__global__ __launch_bounds__(256) void bcast_out(const float* __restrict__ blkpart,
                                                 float* __restrict__ out) {
    const int tid = blockIdx.x * 256 + threadIdx.x;   // 262144
    const int c4 = tid & 255;
    const int row = tid >> 8;                          // b*512 + n
    f32x4 a = (f32x4){0.f, 0.f, 0.f, 0.f};
#pragma unroll
    for (int s = 0; s < 4; ++s) {
        const f32x4 v = ((const f32x4*)blkpart)[(s << 18) + (row << 8) + c4];
        a += v;
    }
    const int b = row >> 9, n = row & 511;
    f32x4* dst = (f32x4*)out + (((size_t)b * 8192 + n * 16) << 8) + c4;
#pragma unroll
    for (int rep = 0; rep < 16; ++rep)
        __builtin_nontemporal_store(a, dst + ((size_t)rep << 8));
}

// ---------------------------------------------------------------------------
extern "C" void kernel_launch(void* const* d_in, const int* in_sizes, int n_in,
                              void* d_out, int out_size, void* d_ws, size_t ws_size,
                              hipStream_t stream) {
    const float* hid  = (const float*)d_in[0];
    const float* enc  = (const float*)d_in[1];
    const int*   mask = (const int*)d_in[2];
    const float* Wq   = (const float*)d_in[3];
    const float* Wk   = (const float*)d_in[4];
    const float* Wv   = (const float*)d_in[5];
    const float* Wo   = (const float*)d_in[6];
    float* out = (float*)d_out;

    char* ws = (char*)d_ws;
    size_t off = 0;
    auto alloc = [&](size_t bytes) -> char* {
        char* p = ws + off;
        off += (bytes + 255) & ~(size_t)255;
        return p;
    };
    u16* Wq_t  = (u16*)alloc((size_t)1024 * 1024 * 2);
    u16* Wkv_t = (u16*)alloc((size_t)512 * 1024 * 2);
    u16* Wo_t  = (u16*)alloc((size_t)1024 * 1024 * 2);
    u16* encb  = (u16*)alloc((size_t)8192 * 1024 * 2);     // 16 MB
    u16* poolb = (u16*)alloc((size_t)1024 * 1024 * 2);     // 2 MB
    u16* Qa    = (u16*)alloc((size_t)1024 * 1024 * 2);
    u16* Ka    = (u16*)alloc((size_t)8 * 4096 * 64 * 2);   // bf16 [l][d]
    u16* Va    = (u16*)alloc((size_t)8 * 4096 * 64 * 2);   // f16  [d][l], masked
    u16* attn  = (u16*)alloc((size_t)1024 * 1024 * 2);
    u16* mh    = (u16*)alloc((size_t)8192 * 2);            // f16 0/1 mask
    // stream-ordered aliases of encb (16 MB):
    //   flash writes Opart -> combine reads Opart -> gemm_o writes blkpart
    //   -> bcast reads blkpart.  mlpart aliases poolb (dead after Q-GEMM).
    float* Opart   = (float*)encb;   // 4096 tiles x 16x64 fp32 = 16 MB
    float* blkpart = (float*)encb;   // 4 x 1024 x 1024 fp32 = 16 MB
    float* mlpart  = (float*)poolb;  // 4096 x 16 fp32 = 256 KB

    prep_all<<<5633, 256, 0, stream>>>(enc, hid, mask, Wq, Wk, Wv, Wo,
                                       encb, poolb, mh, Wq_t, Wkv_t, Wo_t);
    gemm_qkv<<<768, 256, 0, stream>>>(poolb, encb, Wq_t, Wkv_t, mask, Qa, Ka, Va);
    flash_attn<<<1024, 256, 0, stream>>>(Qa, Ka, Va, mh, Opart, mlpart);
    flash_combine<<<1024, 256, 0, stream>>>(Opart, mlpart, attn);
    gemm_o<<<1024, 256, 0, stream>>>(attn, Wo_t, blkpart);
    bcast_out<<<1024, 256, 0, stream>>>(blkpart, out);
}